// Round 1
// baseline (1649.540 us; speedup 1.0000x reference)
//
#include <hip/hip_runtime.h>

// Problem constants (B,T,NI,NH,NO fixed by the reference)
constexpr int kB  = 64;
constexpr int kT  = 100;
constexpr int kNI = 700;
constexpr int kNH = 512;
constexpr int kNO = 20;
constexpr float TAU   = 0.6f;
constexpr float TAU_O = 0.6f;
constexpr float THR   = 0.6f;
constexpr float LR    = 0.05f;

constexpr size_t BNH = (size_t)kB * kNH;   // 32768
constexpr size_t BNI = (size_t)kB * kNI;   // 44800
constexpr size_t BNO = (size_t)kB * kNO;   // 1280

// Workspace layout (float offsets)
constexpr size_t O_XW   = 0;                               // [T,B,NH] x@w_fc1^T
constexpr size_t O_TIN  = O_XW   + (size_t)kT * BNH;       // [T,B,NI] input trace
constexpr size_t O_HS   = O_TIN  + (size_t)kT * BNI;       // [T+1,B,NH] spikes (row t = hs_{t-1})
constexpr size_t O_HSUR = O_HS   + (size_t)(kT + 1) * BNH; // [T,B,NH] surrogate
constexpr size_t O_ERR  = O_HSUR + (size_t)kT * BNH;       // [T,B,NO] err -> errf (in-place)
constexpr size_t O_M    = O_ERR  + (size_t)kT * BNO;       // [T,B,NH] Lf * hsurr
constexpr size_t O_TREC = O_M    + (size_t)kT * BNH;       // [T,B,NH] rec trace
constexpr size_t O_HM   = O_TREC + (size_t)kT * BNH;       // [B,NH]
constexpr size_t O_OM   = O_HM   + BNH;                    // [B,NO]
constexpr size_t O_OS   = O_OM   + BNO;                    // [B,NO]
constexpr size_t O_PART = O_OS   + BNO;                    // [8,B,NH] rec split-K partials
constexpr size_t O_WT   = O_PART + 8 * BNH;                // [NI,NH] w_fc1 transposed
constexpr size_t O_PGF  = O_WT   + (size_t)kNI * kNH;      // 8 x [NH,NI]
constexpr size_t O_PGR  = O_PGF  + 8ull * kNH * kNI;       // 8 x [NH,NH]
constexpr size_t O_PGO  = O_PGR  + 8ull * kNH * kNH;       // 8 x [NO,NH]
constexpr size_t WS_FLOATS = O_PGO + 8ull * kNO * kNH;     // ~26.7M floats = 107 MB

// d_out layout
constexpr size_t OUT_OS = 0;                                // [B,T,NO]
constexpr size_t OUT_GF = (size_t)kB * kT * kNO;            // 128000
constexpr size_t OUT_GR = OUT_GF + (size_t)kNH * kNI;       // +358400
constexpr size_t OUT_GO = OUT_GR + (size_t)kNH * kNH;       // +262144

// ---- w_fc1 [NH,NI] -> wT [NI,NH] -------------------------------------------
__global__ void k_transpose(const float* __restrict__ w, float* __restrict__ wT) {
    __shared__ float tile[32][33];
    int i0 = blockIdx.x * 32, r0 = blockIdx.y * 32;
    int tx = threadIdx.x, ty = threadIdx.y; // 32 x 8
    #pragma unroll
    for (int k = 0; k < 32; k += 8) {
        int i = i0 + tx;
        tile[ty + k][tx] = (i < kNI) ? w[(size_t)(r0 + ty + k) * kNI + i] : 0.f;
    }
    __syncthreads();
    #pragma unroll
    for (int k = 0; k < 32; k += 8) {
        int i = i0 + ty + k;
        if (i < kNI) wT[(size_t)i * kNH + r0 + tx] = tile[tx][ty + k];
    }
}

// ---- tin[t,b,i] = TAU*tin[t-1] + x[b,t,i] ----------------------------------
__global__ __launch_bounds__(256) void k_tin(const float* __restrict__ x, float* __restrict__ tin) {
    int idx = blockIdx.x * 256 + threadIdx.x;  // < B*NI (44800 = 175*256)
    int b = idx / kNI, i = idx % kNI;
    const float* xp = x + (size_t)b * kT * kNI + i;
    float v = 0.f;
    for (int t = 0; t < kT; t++) {
        v = TAU * v + xp[(size_t)t * kNI];
        tin[(size_t)t * BNI + idx] = v;
    }
}

// ---- XW[t,b,r] = sum_i x[b,t,i]*wT[i,r]  (grid: 100 x 8) --------------------
__global__ __launch_bounds__(256) void k_xw(const float* __restrict__ x,
                                            const float* __restrict__ wT,
                                            float* __restrict__ XW) {
    int t  = blockIdx.x;
    int r0 = blockIdx.y * 64;
    int tid = threadIdx.x;
    int tx = tid & 15, ty = tid >> 4;
    __shared__ float Xs[16][68];  // [kk][b] padded
    __shared__ float Ws[16][64];  // [kk][r]
    float acc[4][4] = {};
    for (int k0 = 0; k0 < kNI; k0 += 16) {
        #pragma unroll
        for (int e = tid; e < 1024; e += 256) {
            int row = e >> 4, kk = e & 15;
            int gk = k0 + kk;
            Xs[kk][row] = (gk < kNI) ? x[((size_t)row * kT + t) * kNI + gk] : 0.f;
        }
        #pragma unroll
        for (int e = tid; e < 1024; e += 256) {
            int kk = e >> 6, c = e & 63;
            int gk = k0 + kk;
            Ws[kk][c] = (gk < kNI) ? wT[(size_t)gk * kNH + r0 + c] : 0.f;
        }
        __syncthreads();
        #pragma unroll
        for (int kk = 0; kk < 16; kk++) {
            float4 av = *(const float4*)&Xs[kk][ty * 4];
            float4 bv = *(const float4*)&Ws[kk][tx * 4];
            float aa[4] = {av.x, av.y, av.z, av.w};
            float bb[4] = {bv.x, bv.y, bv.z, bv.w};
            #pragma unroll
            for (int a = 0; a < 4; a++)
                #pragma unroll
                for (int c = 0; c < 4; c++) acc[a][c] += aa[a] * bb[c];
        }
        __syncthreads();
    }
    #pragma unroll
    for (int a = 0; a < 4; a++) {
        int b = ty * 4 + a;
        float* dst = XW + ((size_t)t * kB + b) * kNH + r0 + tx * 4;
        dst[0] = acc[a][0]; dst[1] = acc[a][1]; dst[2] = acc[a][2]; dst[3] = acc[a][3];
    }
}

// ---- per-step recurrent GEMM, split-K: part[s][b,r] = sum_{j in slice} hs[b,j]*w_rec[j,r]
__global__ __launch_bounds__(256) void k1_rec(int t, const float* __restrict__ hs_base,
                                              const float* __restrict__ w_rec,
                                              float* __restrict__ part) {
    int bx = blockIdx.x, tid = threadIdx.x;       // grid 256
    int s = bx & 7, rt = (bx >> 3) & 7, bt = bx >> 6;
    int b0 = bt * 16, r0 = rt * 64, k0 = s * 64;
    const float* hsrow = hs_base + (size_t)t * BNH;
    __shared__ float Hs[16][17];
    __shared__ float Ws[16][64];
    int tx = tid & 15, ty = tid >> 4;
    float acc[4] = {0.f, 0.f, 0.f, 0.f};
    for (int kc = 0; kc < 64; kc += 16) {
        Hs[ty][tx] = hsrow[(size_t)(b0 + ty) * kNH + k0 + kc + tx];
        #pragma unroll
        for (int e = tid; e < 1024; e += 256) {
            int kk = e >> 6, c = e & 63;
            Ws[kk][c] = w_rec[(size_t)(k0 + kc + kk) * kNH + r0 + c];
        }
        __syncthreads();
        #pragma unroll
        for (int kk = 0; kk < 16; kk++) {
            float h = Hs[ty][kk];
            float4 wv = *(const float4*)&Ws[kk][tx * 4];
            acc[0] += h * wv.x; acc[1] += h * wv.y; acc[2] += h * wv.z; acc[3] += h * wv.w;
        }
        __syncthreads();
    }
    float* p = part + (size_t)s * BNH + (size_t)(b0 + ty) * kNH + r0 + tx * 4;
    p[0] = acc[0]; p[1] = acc[1]; p[2] = acc[2]; p[3] = acc[3];
}

// ---- per-step LIF update (+ output layer for step t-1) ----------------------
__global__ __launch_bounds__(256) void k2_update(int t, int HB, float* __restrict__ ws,
                                                 const float* __restrict__ label,
                                                 const float* __restrict__ w_out,
                                                 float* __restrict__ dout) {
    int bx = blockIdx.x, tid = threadIdx.x;
    if (bx < HB) {
        size_t idx = (size_t)bx * 256 + tid;
        float hi = ws[O_XW + (size_t)t * BNH + idx];
        #pragma unroll
        for (int s = 0; s < 8; s++) hi += ws[O_PART + (size_t)s * BNH + idx];
        float hm_o = ws[O_HM + idx];
        float hs_o = ws[O_HS + (size_t)t * BNH + idx];
        float hm_n = TAU * hm_o * (1.f - hs_o) + hi;
        float spike = (hm_n >= THR) ? 1.f : 0.f;
        ws[O_HM + idx] = hm_n;
        ws[O_HS + (size_t)(t + 1) * BNH + idx] = spike;
        ws[O_HSUR + (size_t)t * BNH + idx] =
            TAU * fmaxf(0.f, 1.f - fabsf(hm_n - THR) * (1.f / THR));
    } else {
        if (t < 1) return;
        int b = bx - HB;          // one block per batch sample
        int tm1 = t - 1;
        const float* hsrow = ws + O_HS + (size_t)t * BNH + (size_t)b * kNH;  // hs_{t-1}
        int lane = tid & 63, w = tid >> 6;
        float h[8];
        #pragma unroll
        for (int k = 0; k < 8; k++) h[k] = hsrow[lane + 64 * k];
        #pragma unroll
        for (int q = 0; q < 5; q++) {
            int o = w * 5 + q;
            float p = 0.f;
            #pragma unroll
            for (int k = 0; k < 8; k++) p += h[k] * w_out[(size_t)o * kNH + lane + 64 * k];
            #pragma unroll
            for (int off = 32; off >= 1; off >>= 1) p += __shfl_xor(p, off);
            if (lane == 0) {
                int lidx = b * kNO + o;
                float om_o = ws[O_OM + lidx], os_o = ws[O_OS + lidx];
                float om_n = TAU * om_o * (1.f - os_o) + p;
                float os_n = (om_n >= THR) ? 1.f : 0.f;
                ws[O_OM + lidx] = om_n; ws[O_OS + lidx] = os_n;
                float e = os_n - label[((size_t)b * kT + tm1) * kNO + o];
                ws[O_ERR + (size_t)tm1 * BNO + lidx] = e;
                dout[(size_t)b * kT * kNO + (size_t)tm1 * kNO + o] = os_n;
            }
        }
    }
}

// ---- reverse kappa filter of err (in place) --------------------------------
__global__ void k_errscan(float* __restrict__ ws) {
    int idx = blockIdx.x * 256 + threadIdx.x;  // < 1280
    float v = 0.f;
    for (int t = kT - 1; t >= 0; t--) {
        float* p = ws + O_ERR + (size_t)t * BNO + idx;
        v = *p + TAU_O * v;
        *p = v;
    }
}

// ---- M[tb,r] = (errf[tb,:] @ w_out)[r] * hsurr[tb,r]  (block = 8 tb rows) ---
__global__ __launch_bounds__(256) void k_M(float* __restrict__ ws, const float* __restrict__ w_out) {
    __shared__ float wo[kNO * kNH];  // 40 KB
    __shared__ float ef[8 * kNO];
    int tid = threadIdx.x;
    int tb0 = blockIdx.x * 8;
    for (int e = tid; e < kNO * kNH; e += 256) wo[e] = w_out[e];
    for (int e = tid; e < 8 * kNO; e += 256) ef[e] = ws[O_ERR + (size_t)tb0 * kNO + e];
    __syncthreads();
    for (int e = tid; e < 8 * kNH; e += 256) {
        int tbl = e >> 9, r = e & 511;
        float s = 0.f;
        #pragma unroll
        for (int o = 0; o < kNO; o++) s += ef[tbl * kNO + o] * wo[o * kNH + r];
        size_t g = (size_t)(tb0 + tbl) * kNH + r;
        ws[O_M + g] = s * ws[O_HSUR + g];
    }
}

// ---- trec[t,b,j] = TAU*trec[t-1] + hs_{t-1} --------------------------------
__global__ void k_trec(float* __restrict__ ws) {
    size_t idx = (size_t)blockIdx.x * 256 + threadIdx.x;  // < BNH
    float v = 0.f;
    for (int t = 0; t < kT; t++) {
        v = TAU * v + ws[O_HS + (size_t)t * BNH + idx];
        ws[O_TREC + (size_t)t * BNH + idx] = v;
    }
}

// ---- generic split-K TN GEMM: Cpart[s][m,n] = sum_{k in slice} A[k,m]*B[k,n]
__global__ __launch_bounds__(256) void k_gemmTN(const float* __restrict__ A,
                                                const float* __restrict__ Bm,
                                                float* __restrict__ Cpart,
                                                int Mdim, int Ndim, int lda, int ldb,
                                                int Mtiles, int S, int K) {
    int bx = blockIdx.x, tid = threadIdx.x;
    int s = bx % S;
    int tmp = bx / S;
    int mt = tmp % Mtiles, nt = tmp / Mtiles;
    int m0 = mt * 64, n0 = nt * 64;
    int Kc = K / S, k0 = s * Kc;
    __shared__ float As[16][64];
    __shared__ float Bs[16][64];
    int tx = tid & 15, ty = tid >> 4;
    float acc[4][4] = {};
    for (int kb = 0; kb < Kc; kb += 16) {
        #pragma unroll
        for (int e = tid; e < 1024; e += 256) {
            int kk = e >> 6, c = e & 63;
            size_t gk = (size_t)(k0 + kb + kk);
            As[kk][c] = (m0 + c < Mdim) ? A[gk * lda + m0 + c] : 0.f;
            Bs[kk][c] = (n0 + c < Ndim) ? Bm[gk * ldb + n0 + c] : 0.f;
        }
        __syncthreads();
        #pragma unroll
        for (int kk = 0; kk < 16; kk++) {
            float4 av = *(const float4*)&As[kk][ty * 4];
            float4 bv = *(const float4*)&Bs[kk][tx * 4];
            float aa[4] = {av.x, av.y, av.z, av.w};
            float bb[4] = {bv.x, bv.y, bv.z, bv.w};
            #pragma unroll
            for (int a = 0; a < 4; a++)
                #pragma unroll
                for (int c = 0; c < 4; c++) acc[a][c] += aa[a] * bb[c];
        }
        __syncthreads();
    }
    float* Cs = Cpart + (size_t)s * Mdim * Ndim;
    #pragma unroll
    for (int a = 0; a < 4; a++) {
        int m = m0 + ty * 4 + a;
        if (m >= Mdim) continue;
        #pragma unroll
        for (int c = 0; c < 4; c++) {
            int n = n0 + tx * 4 + c;
            if (n < Ndim) Cs[(size_t)m * Ndim + n] = acc[a][c];
        }
    }
}

// ---- reduce 8 split-K slices -> d_out (applies LR) --------------------------
__global__ void k_reduce(const float* __restrict__ ws, float* __restrict__ dout) {
    int idx = blockIdx.x * 256 + threadIdx.x;
    const int NGF = kNH * kNI, NGR = kNH * kNH, NGO = kNO * kNH;
    size_t src, dst; int stride;
    if (idx < NGF)                  { src = O_PGF + idx;              stride = NGF; dst = OUT_GF + idx; }
    else if (idx < NGF + NGR)       { int j = idx - NGF;              src = O_PGR + j; stride = NGR; dst = OUT_GR + j; }
    else if (idx < NGF + NGR + NGO) { int j = idx - NGF - NGR;        src = O_PGO + j; stride = NGO; dst = OUT_GO + j; }
    else return;
    float s = 0.f;
    #pragma unroll
    for (int k = 0; k < 8; k++) s += ws[src + (size_t)k * stride];
    dout[dst] = LR * s;
}

extern "C" void kernel_launch(void* const* d_in, const int* in_sizes, int n_in,
                              void* d_out, int out_size, void* d_ws, size_t ws_size,
                              hipStream_t stream) {
    (void)in_sizes; (void)n_in; (void)out_size;
    const float* x     = (const float*)d_in[0];
    const float* label = (const float*)d_in[1];
    const float* w_fc1 = (const float*)d_in[3];
    const float* w_rec = (const float*)d_in[4];
    const float* w_out = (const float*)d_in[5];
    float* out = (float*)d_out;
    float* ws  = (float*)d_ws;

    if (ws_size < WS_FLOATS * sizeof(float)) return;  // insufficient scratch — fail visibly

    // init state: hs row 0 (= hs_{-1}), hm, om, os
    hipMemsetAsync(ws + O_HS, 0, BNH * sizeof(float), stream);
    hipMemsetAsync(ws + O_HM, 0, (BNH + 2 * BNO) * sizeof(float), stream);

    k_transpose<<<dim3(22, 16), dim3(32, 8), 0, stream>>>(w_fc1, ws + O_WT);
    k_tin<<<175, 256, 0, stream>>>(x, ws + O_TIN);
    k_xw<<<dim3(kT, 8), 256, 0, stream>>>(x, ws + O_WT, ws + O_XW);

    for (int t = 0; t < kT; t++) {
        k1_rec<<<256, 256, 0, stream>>>(t, ws + O_HS, w_rec, ws + O_PART);
        k2_update<<<128 + kB, 256, 0, stream>>>(t, 128, ws, label, w_out, out);
    }
    k2_update<<<kB, 256, 0, stream>>>(kT, 0, ws, label, w_out, out);  // output layer t=99

    k_errscan<<<5, 256, 0, stream>>>(ws);
    k_M<<<kT * kB / 8, 256, 0, stream>>>(ws, w_out);
    k_trec<<<128, 256, 0, stream>>>(ws);

    const int K = kT * kB;  // 6400
    // gf: [512 x 700], A = M (lda=512), B = tin (ldb=700)
    k_gemmTN<<<8 * 11 * 8, 256, 0, stream>>>(ws + O_M, ws + O_TIN, ws + O_PGF,
                                             kNH, kNI, kNH, kNI, 8, 8, K);
    // gr: [512 x 512], B = trec
    k_gemmTN<<<8 * 8 * 8, 256, 0, stream>>>(ws + O_M, ws + O_TREC, ws + O_PGR,
                                            kNH, kNH, kNH, kNH, 8, 8, K);
    // go: [20 x 512], A = errf (lda=20), B = hs rows 1..T
    k_gemmTN<<<1 * 8 * 8, 256, 0, stream>>>(ws + O_ERR, ws + O_HS + BNH, ws + O_PGO,
                                            kNO, kNH, kNO, kNH, 1, 8, K);

    k_reduce<<<2464, 256, 0, stream>>>(ws, out);
}

// Round 2
// 1049.251 us; speedup vs baseline: 1.5721x; 1.5721x over previous
//
#include <hip/hip_runtime.h>

// Problem constants (B,T,NI,NH,NO fixed by the reference)
constexpr int kB  = 64;
constexpr int kT  = 100;
constexpr int kNI = 700;
constexpr int kNH = 512;
constexpr int kNO = 20;
constexpr float TAU   = 0.6f;
constexpr float TAU_O = 0.6f;
constexpr float THR   = 0.6f;
constexpr float LR    = 0.05f;

constexpr size_t BNH = (size_t)kB * kNH;   // 32768
constexpr size_t BNI = (size_t)kB * kNI;   // 44800
constexpr size_t BNO = (size_t)kB * kNO;   // 1280

constexpr int kKP = 704;                   // padded K for xw GEMM (704 = 44*16)

// Workspace layout (float offsets). PGF (16 slices of [512,700]) is overlaid
// on XW+HSUR, which are dead by the time the gf GEMM runs.
constexpr size_t O_XW   = 0;                               // [T,B,NH]
constexpr size_t O_HSUR = O_XW   + (size_t)kT * BNH;       // [T,B,NH]
constexpr size_t O_PGF  = 0;                               // overlay: 16 x [NH,NI] = 5,734,400 < 6,553,600
constexpr size_t O_TIN  = O_HSUR + (size_t)kT * BNH;       // [T,B,NI]
constexpr size_t O_HS   = O_TIN  + (size_t)kT * BNI;       // [T+1,B,NH] (row t = hs_{t-1})
constexpr size_t O_ERR  = O_HS   + (size_t)(kT + 1) * BNH; // [T,B,NO] err -> errf in place
constexpr size_t O_M    = O_ERR  + (size_t)kT * BNO;       // [T,B,NH] LR*(errf@w_out)*hsur
constexpr size_t O_TREC = O_M    + (size_t)kT * BNH;       // [T,B,NH]
constexpr size_t O_WT   = O_TREC + (size_t)kT * BNH;       // [704,NH] w_fc1^T zero-padded
constexpr size_t O_PGO  = O_WT   + (size_t)kKP * kNH;      // 8 x [NO,NH]
constexpr size_t O_PGR  = O_PGO  + 8ull * kNO * kNH;       // 16 x [NH,NH]
constexpr size_t WS_FLOATS = O_PGR + 16ull * kNH * kNH;    // 25,661,440 floats = 102.6 MB

// d_out layout
constexpr size_t OUT_GF = (size_t)kB * kT * kNO;
constexpr size_t OUT_GR = OUT_GF + (size_t)kNH * kNI;
constexpr size_t OUT_GO = OUT_GR + (size_t)kNH * kNH;

// ---- w_fc1 [NH,NI] -> wT [704,NH], rows 700..703 zero -----------------------
__global__ void k_transpose(const float* __restrict__ w, float* __restrict__ wT) {
    __shared__ float tile[32][33];
    int i0 = blockIdx.x * 32, r0 = blockIdx.y * 32;
    int tx = threadIdx.x, ty = threadIdx.y; // 32 x 8
    #pragma unroll
    for (int k = 0; k < 32; k += 8) {
        int i = i0 + tx;
        tile[ty + k][tx] = (i < kNI) ? w[(size_t)(r0 + ty + k) * kNI + i] : 0.f;
    }
    __syncthreads();
    #pragma unroll
    for (int k = 0; k < 32; k += 8) {
        int i = i0 + ty + k;  // < 704 by grid
        wT[(size_t)i * kNH + r0 + tx] = tile[tx][ty + k];
    }
}

// ---- tin[t,b,i] = TAU*tin[t-1] + x[b,t,i] ----------------------------------
__global__ __launch_bounds__(256) void k_tin(const float* __restrict__ x, float* __restrict__ tin) {
    int idx = blockIdx.x * 256 + threadIdx.x;  // < B*NI
    int b = idx / kNI, i = idx % kNI;
    const float* xp = x + (size_t)b * kT * kNI + i;
    float v = 0.f;
    for (int t = 0; t < kT; t++) {
        v = TAU * v + xp[(size_t)t * kNI];
        tin[(size_t)t * BNI + idx] = v;
    }
}

// ---- XW = Xperm @ wT : C[m,n], m=t*64+b (6400), n<512, K=704 (padded) -------
// 128x128 tile, 8x8 per thread. grid = 50*4
__global__ __launch_bounds__(256) void k_xw2(const float* __restrict__ x,
                                             const float* __restrict__ wT,
                                             float* __restrict__ XW) {
    int bx = blockIdx.x;
    int mt = bx % 50, nt = bx / 50;
    int m0 = mt * 128, n0 = nt * 128;
    int tid = threadIdx.x, tx = tid & 15, ty = tid >> 4;
    __shared__ float As[128][20];  // [m][k] pad to 20 (16B-aligned rows)
    __shared__ float Bs[16][128];
    float acc[8][8] = {};
    int arow = tid >> 1, ahalf = tid & 1;
    int bb = (m0 + arow) & 63, tt = (m0 + arow) >> 6;
    const float* ap = x + ((size_t)bb * kT + tt) * kNI;
    for (int k0 = 0; k0 < kKP; k0 += 16) {
        #pragma unroll
        for (int u = 0; u < 2; u++) {
            int k = k0 + ahalf * 8 + u * 4;
            float4 v = (k + 3 < kNI) ? *(const float4*)(ap + k)
                                     : make_float4(0.f, 0.f, 0.f, 0.f);
            *(float4*)&As[arow][ahalf * 8 + u * 4] = v;
        }
        #pragma unroll
        for (int u = 0; u < 2; u++) {
            int f = tid * 2 + u;
            int kk = f >> 5, c4 = f & 31;
            *(float4*)&Bs[kk][c4 * 4] =
                *(const float4*)(wT + (size_t)(k0 + kk) * kNH + n0 + c4 * 4);
        }
        __syncthreads();
        #pragma unroll
        for (int kk = 0; kk < 16; kk++) {
            float av[8];
            #pragma unroll
            for (int i = 0; i < 4; i++) {
                av[i]     = As[ty * 4 + i][kk];
                av[4 + i] = As[64 + ty * 4 + i][kk];
            }
            float4 b0 = *(const float4*)&Bs[kk][tx * 4];
            float4 b1 = *(const float4*)&Bs[kk][64 + tx * 4];
            float bvv[8] = {b0.x, b0.y, b0.z, b0.w, b1.x, b1.y, b1.z, b1.w};
            #pragma unroll
            for (int i = 0; i < 8; i++)
                #pragma unroll
                for (int j = 0; j < 8; j++) acc[i][j] += av[i] * bvv[j];
        }
        __syncthreads();
    }
    #pragma unroll
    for (int i = 0; i < 8; i++) {
        int m = m0 + ((i < 4) ? (ty * 4 + i) : (64 + ty * 4 + i - 4));
        float* dst = XW + (size_t)m * kNH + n0;
        *(float4*)(dst + tx * 4)      = make_float4(acc[i][0], acc[i][1], acc[i][2], acc[i][3]);
        *(float4*)(dst + 64 + tx * 4) = make_float4(acc[i][4], acc[i][5], acc[i][6], acc[i][7]);
    }
}

// ---- fused forward: one WG per batch sample, loops all T steps --------------
__global__ __launch_bounds__(256) void k_forward(float* __restrict__ ws,
                                                 const float* __restrict__ label,
                                                 const float* __restrict__ w_rec,
                                                 const float* __restrict__ w_out,
                                                 float* __restrict__ dout) {
    int b = blockIdx.x;
    int tid = threadIdx.x;
    int lane = tid & 63, w = tid >> 6;
    __shared__ float hs_ld[512];
    __shared__ int   list[512];
    __shared__ float wout_ld[kNO * kNH];  // 40 KB
    __shared__ float om_ld[kNO], os_ld[kNO];
    __shared__ int   cnt[8];
    for (int e = tid; e < kNO * kNH; e += 256) wout_ld[e] = w_out[e];
    hs_ld[tid] = 0.f; hs_ld[tid + 256] = 0.f;
    if (tid < kNO) { om_ld[tid] = 0.f; os_ld[tid] = 0.f; }
    float hm0 = 0.f, hm1 = 0.f;
    int nact = 0;
    const unsigned long long below = (1ull << lane) - 1ull;
    __syncthreads();

    for (int t = 0; t < kT; t++) {
        // --- A: rec = sum over active j (ascending) of w_rec[j,:] ---
        float rec0 = 0.f, rec1 = 0.f;
        int i = 0;
        for (; i + 8 <= nact; i += 8) {
            float a[8], c[8];
            #pragma unroll
            for (int u = 0; u < 8; u++) {
                int j = list[i + u];
                a[u] = w_rec[j * kNH + tid];
                c[u] = w_rec[j * kNH + tid + 256];
            }
            #pragma unroll
            for (int u = 0; u < 8; u++) { rec0 += a[u]; rec1 += c[u]; }
        }
        for (; i < nact; i++) {
            int j = list[i];
            rec0 += w_rec[j * kNH + tid];
            rec1 += w_rec[j * kNH + tid + 256];
        }
        // --- B: membrane update + spikes (own r only; no cross-thread LDS hazard) ---
        size_t xwo = O_XW + (size_t)t * BNH + (size_t)b * kNH;
        float xw0 = ws[xwo + tid], xw1 = ws[xwo + tid + 256];
        float hso0 = hs_ld[tid], hso1 = hs_ld[tid + 256];
        hm0 = TAU * hm0 * (1.f - hso0) + (xw0 + rec0);
        hm1 = TAU * hm1 * (1.f - hso1) + (xw1 + rec1);
        bool v0 = (hm0 >= THR), v1 = (hm1 >= THR);
        float sp0 = v0 ? 1.f : 0.f, sp1 = v1 ? 1.f : 0.f;
        hs_ld[tid] = sp0; hs_ld[tid + 256] = sp1;
        size_t hso = O_HS + (size_t)(t + 1) * BNH + (size_t)b * kNH;
        ws[hso + tid] = sp0; ws[hso + tid + 256] = sp1;
        size_t suo = O_HSUR + (size_t)t * BNH + (size_t)b * kNH;
        ws[suo + tid]       = TAU * fmaxf(0.f, 1.f - fabsf(hm0 - THR) * (1.f / THR));
        ws[suo + tid + 256] = TAU * fmaxf(0.f, 1.f - fabsf(hm1 - THR) * (1.f / THR));
        unsigned long long m0 = __ballot(v0);
        unsigned long long m1 = __ballot(v1);
        if (lane == 0) { cnt[w] = __popcll(m0); cnt[4 + w] = __popcll(m1); }
        __syncthreads();
        // --- L: ordered active list for next step ---
        int bases[8], tot = 0;
        #pragma unroll
        for (int k2 = 0; k2 < 8; k2++) { bases[k2] = tot; tot += cnt[k2]; }
        nact = tot;
        if (v0) list[bases[w]     + __popcll(m0 & below)] = (w << 6) + lane;
        if (v1) list[bases[4 + w] + __popcll(m1 & below)] = (w << 6) + lane + 256;
        // --- C: output LIF layer (uses this step's spikes) ---
        float h[8];
        #pragma unroll
        for (int k = 0; k < 8; k++) h[k] = hs_ld[lane + 64 * k];
        #pragma unroll
        for (int q = 0; q < 5; q++) {
            int o = w * 5 + q;
            float p = 0.f;
            #pragma unroll
            for (int k = 0; k < 8; k++) p += h[k] * wout_ld[o * kNH + lane + 64 * k];
            #pragma unroll
            for (int off = 32; off >= 1; off >>= 1) p += __shfl_xor(p, off);
            if (lane == 0) {
                float om = om_ld[o], os = os_ld[o];
                float om_n = TAU * om * (1.f - os) + p;
                float os_n = (om_n >= THR) ? 1.f : 0.f;
                om_ld[o] = om_n; os_ld[o] = os_n;
                float e = os_n - label[((size_t)b * kT + t) * kNO + o];
                ws[O_ERR + (size_t)t * BNO + (size_t)b * kNO + o] = e;
                dout[((size_t)b * kT + t) * kNO + o] = os_n;
            }
        }
        __syncthreads();  // guards list/hs_ld/om reads vs next iteration's writes
    }
}

// ---- reverse kappa filter of err (in place) --------------------------------
__global__ void k_errscan(float* __restrict__ ws) {
    int idx = blockIdx.x * 256 + threadIdx.x;  // < 1280
    float v = 0.f;
    for (int t = kT - 1; t >= 0; t--) {
        float* p = ws + O_ERR + (size_t)t * BNO + idx;
        v = *p + TAU_O * v;
        *p = v;
    }
}

// ---- M[tb,r] = LR * (errf[tb,:] @ w_out)[r] * hsur[tb,r] --------------------
__global__ __launch_bounds__(256) void k_M(float* __restrict__ ws, const float* __restrict__ w_out) {
    __shared__ float wo[kNO * kNH];
    __shared__ float ef[8 * kNO];
    int tid = threadIdx.x;
    int tb0 = blockIdx.x * 8;
    for (int e = tid; e < kNO * kNH; e += 256) wo[e] = w_out[e];
    for (int e = tid; e < 8 * kNO; e += 256) ef[e] = ws[O_ERR + (size_t)tb0 * kNO + e];
    __syncthreads();
    for (int e = tid; e < 8 * kNH; e += 256) {
        int tbl = e >> 9, r = e & 511;
        float s = 0.f;
        #pragma unroll
        for (int o = 0; o < kNO; o++) s += ef[tbl * kNO + o] * wo[o * kNH + r];
        size_t g = (size_t)(tb0 + tbl) * kNH + r;
        ws[O_M + g] = LR * s * ws[O_HSUR + g];
    }
}

// ---- trec[t,b,j] = TAU*trec[t-1] + hs_{t-1} --------------------------------
__global__ void k_trec(float* __restrict__ ws) {
    size_t idx = (size_t)blockIdx.x * 256 + threadIdx.x;  // < BNH
    float v = 0.f;
    for (int t = 0; t < kT; t++) {
        v = TAU * v + ws[O_HS + (size_t)t * BNH + idx];
        ws[O_TREC + (size_t)t * BNH + idx] = v;
    }
}

// ---- TN GEMM 128x128x(Kc=400), 8x8/thread, 16 K-slices ----------------------
// Cpart[s][m,n] = sum_{k in slice s} A[k,m]*B[k,n]; M=512 fixed.
__global__ __launch_bounds__(256) void k_gemm_tn(const float* __restrict__ A,
                                                 const float* __restrict__ Bm,
                                                 float* __restrict__ Cpart,
                                                 int Ndim) {
    int bx = blockIdx.x;
    int s = bx & 15, tmp = bx >> 4;
    int mt = tmp & 3, nt = tmp >> 2;
    int m0 = mt * 128, n0 = nt * 128;
    int k0 = s * 400;
    int tid = threadIdx.x, tx = tid & 15, ty = tid >> 4;
    __shared__ float As[16][128];
    __shared__ float Bs[16][128];
    float acc[8][8] = {};
    for (int kb = 0; kb < 400; kb += 16) {
        #pragma unroll
        for (int u = 0; u < 2; u++) {
            int f = tid * 2 + u;
            int kk = f >> 5, c4 = f & 31;
            size_t gk = (size_t)(k0 + kb + kk);
            *(float4*)&As[kk][c4 * 4] = *(const float4*)(A + gk * kNH + m0 + c4 * 4);
            int n = n0 + c4 * 4;
            *(float4*)&Bs[kk][c4 * 4] = (n < Ndim) ? *(const float4*)(Bm + gk * Ndim + n)
                                                   : make_float4(0.f, 0.f, 0.f, 0.f);
        }
        __syncthreads();
        #pragma unroll
        for (int kk = 0; kk < 16; kk++) {
            float4 a0 = *(const float4*)&As[kk][ty * 4];
            float4 a1 = *(const float4*)&As[kk][64 + ty * 4];
            float4 b0 = *(const float4*)&Bs[kk][tx * 4];
            float4 b1 = *(const float4*)&Bs[kk][64 + tx * 4];
            float av[8] = {a0.x, a0.y, a0.z, a0.w, a1.x, a1.y, a1.z, a1.w};
            float bv[8] = {b0.x, b0.y, b0.z, b0.w, b1.x, b1.y, b1.z, b1.w};
            #pragma unroll
            for (int i = 0; i < 8; i++)
                #pragma unroll
                for (int j = 0; j < 8; j++) acc[i][j] += av[i] * bv[j];
        }
        __syncthreads();
    }
    float* C = Cpart + (size_t)s * kNH * Ndim;
    #pragma unroll
    for (int i = 0; i < 8; i++) {
        int m = m0 + ((i < 4) ? (ty * 4 + i) : (64 + ty * 4 + i - 4));
        float* dst = C + (size_t)m * Ndim;
        int n = n0 + tx * 4;
        if (n < Ndim)
            *(float4*)(dst + n) = make_float4(acc[i][0], acc[i][1], acc[i][2], acc[i][3]);
        if (n + 64 < Ndim)
            *(float4*)(dst + n + 64) = make_float4(acc[i][4], acc[i][5], acc[i][6], acc[i][7]);
    }
}

// ---- small TN GEMM for go (M=20): Cpart[s][m,n] over K/8 slices -------------
__global__ __launch_bounds__(256) void k_gemmTN_go(const float* __restrict__ A,
                                                   const float* __restrict__ Bm,
                                                   float* __restrict__ Cpart) {
    int bx = blockIdx.x, tid = threadIdx.x;  // grid 64 = 8 s * 8 nt
    int s = bx & 7, nt = bx >> 3;
    int n0 = nt * 64, k0 = s * 800;
    __shared__ float As[16][64];
    __shared__ float Bs[16][64];
    int tx = tid & 15, ty = tid >> 4;
    float acc[4][4] = {};
    for (int kb = 0; kb < 800; kb += 16) {
        #pragma unroll
        for (int e = tid; e < 1024; e += 256) {
            int kk = e >> 6, c = e & 63;
            size_t gk = (size_t)(k0 + kb + kk);
            As[kk][c] = (c < kNO) ? A[gk * kNO + c] : 0.f;
            Bs[kk][c] = Bm[gk * kNH + n0 + c];
        }
        __syncthreads();
        #pragma unroll
        for (int kk = 0; kk < 16; kk++) {
            float4 av = *(const float4*)&As[kk][ty * 4];
            float4 bv = *(const float4*)&Bs[kk][tx * 4];
            float aa[4] = {av.x, av.y, av.z, av.w};
            float bb[4] = {bv.x, bv.y, bv.z, bv.w};
            #pragma unroll
            for (int a = 0; a < 4; a++)
                #pragma unroll
                for (int c = 0; c < 4; c++) acc[a][c] += aa[a] * bb[c];
        }
        __syncthreads();
    }
    float* Cs = Cpart + (size_t)s * kNO * kNH;
    #pragma unroll
    for (int a = 0; a < 4; a++) {
        int m = ty * 4 + a;
        if (m >= kNO) continue;
        #pragma unroll
        for (int c = 0; c < 4; c++)
            Cs[(size_t)m * kNH + n0 + tx * 4 + c] = acc[a][c];
    }
}

// ---- reductions -------------------------------------------------------------
__global__ void k_reduce_gfgr(const float* __restrict__ ws, float* __restrict__ dout) {
    int idx = blockIdx.x * 256 + threadIdx.x;  // < 620544
    const int NGF = kNH * kNI, NGR = kNH * kNH;
    float s = 0.f;
    if (idx < NGF) {
        #pragma unroll
        for (int k = 0; k < 16; k++) s += ws[O_PGF + (size_t)k * NGF + idx];
        dout[OUT_GF + idx] = s;   // LR folded into M
    } else {
        int j = idx - NGF;
        #pragma unroll
        for (int k = 0; k < 16; k++) s += ws[O_PGR + (size_t)k * NGR + j];
        dout[OUT_GR + j] = s;
    }
}

__global__ void k_reduce_go(const float* __restrict__ ws, float* __restrict__ dout) {
    int idx = blockIdx.x * 256 + threadIdx.x;  // < 10240
    const int NGO = kNO * kNH;
    float s = 0.f;
    #pragma unroll
    for (int k = 0; k < 8; k++) s += ws[O_PGO + (size_t)k * NGO + idx];
    dout[OUT_GO + idx] = LR * s;
}

extern "C" void kernel_launch(void* const* d_in, const int* in_sizes, int n_in,
                              void* d_out, int out_size, void* d_ws, size_t ws_size,
                              hipStream_t stream) {
    (void)in_sizes; (void)n_in; (void)out_size;
    const float* x     = (const float*)d_in[0];
    const float* label = (const float*)d_in[1];
    const float* w_fc1 = (const float*)d_in[3];
    const float* w_rec = (const float*)d_in[4];
    const float* w_out = (const float*)d_in[5];
    float* out = (float*)d_out;
    float* ws  = (float*)d_ws;

    if (ws_size < WS_FLOATS * sizeof(float)) return;

    // hs row 0 (= hs_{-1}) must be zero for trec scan
    hipMemsetAsync(ws + O_HS, 0, BNH * sizeof(float), stream);

    k_transpose<<<dim3(22, 16), dim3(32, 8), 0, stream>>>(w_fc1, ws + O_WT);
    k_tin<<<175, 256, 0, stream>>>(x, ws + O_TIN);
    k_xw2<<<200, 256, 0, stream>>>(x, ws + O_WT, ws + O_XW);

    k_forward<<<kB, 256, 0, stream>>>(ws, label, w_rec, w_out, out);

    k_errscan<<<5, 256, 0, stream>>>(ws);
    k_M<<<kT * kB / 8, 256, 0, stream>>>(ws, w_out);
    k_trec<<<128, 256, 0, stream>>>(ws);

    // gf: A=M [6400,512], B=tin [6400,700] -> 16 slices overlaid on XW/HSUR
    k_gemm_tn<<<16 * 4 * 6, 256, 0, stream>>>(ws + O_M, ws + O_TIN, ws + O_PGF, kNI);
    // gr: B=trec [6400,512]
    k_gemm_tn<<<16 * 4 * 4, 256, 0, stream>>>(ws + O_M, ws + O_TREC, ws + O_PGR, kNH);
    // go: A=errf [6400,20], B=hs rows 1..T
    k_gemmTN_go<<<64, 256, 0, stream>>>(ws + O_ERR, ws + O_HS + BNH, ws + O_PGO);

    k_reduce_gfgr<<<2424, 256, 0, stream>>>(ws, out);
    k_reduce_go<<<40, 256, 0, stream>>>(ws, out);
}